// Round 9
// baseline (2141.226 us; speedup 1.0000x reference)
//
#include <hip/hip_runtime.h>
#include <hip/hip_bf16.h>

#define NSEQ 512
#define SEGS 511     // L-1
#define CIN  32

__device__ __forceinline__ float rl(float v, int lane) {
    return __int_as_float(__builtin_amdgcn_readlane(__float_as_int(v), lane));
}

__device__ __forceinline__ float tanhf_fast(float x) {
    // tanh(x) = sign(x) * (1 - e) / (1 + e),  e = exp(-2|x|)  — no overflow path
    float ax = fabsf(x);
    float e = __expf(-2.0f * ax);
#if __has_builtin(__builtin_amdgcn_rcpf)
    float r = (1.0f - e) * __builtin_amdgcn_rcpf(1.0f + e);
#else
    float r = (1.0f - e) / (1.0f + e);
#endif
    return copysignf(r, x);
}

// Block = ONE sequence x 4 waves (256 thr), grid = 512 -> 2 blocks/CU,
// 8 waves/CU = 2 waves/SIMD. r8 proved weights-in-registers works
// (waves_per_eu) but sat at 1 wave/SIMD with ~900 cyc/stage of naked stall.
// This round: 2D split with NO lane duplication so the wave count doubles
// while total issue stays constant -> co-resident waves hide each other's
// stalls.
//   wave w: pair = w>>1 (h-column half), half = w&1 (mm1 K-half)
//   mm1: col = 64*pair + lane; K-rows [48*half, 48*half+48)
//        -> pairwise h-partial exchange (1 write + 1 read + barrier)
//   mm2: 4-way K-split, rows [32w, 32w+32) = own h lanes [32*half, ..)
//        -> 4-way z-partial exchange (1 write + 4 reads + barrier)
// Register ask ~150 VGPR < 256: amdgpu_waves_per_eu(2,2) gives a 256-VGPR
// budget (no remat pressure, r7's failure mode) while allowing 2 waves/SIMD.
__attribute__((amdgpu_waves_per_eu(2, 2)))
__global__ __launch_bounds__(256) void node_kernel(
    const float* __restrict__ cA, const float* __restrict__ cB,
    const float* __restrict__ cC, const float* __restrict__ cD,
    const int*   __restrict__ final_index,
    const float* __restrict__ W_init, const float* __restrict__ b_init,
    const float* __restrict__ W1, const float* __restrict__ b1,
    const float* __restrict__ W2, const float* __restrict__ b2,
    const float* __restrict__ W_out, const float* __restrict__ b_out,
    float* __restrict__ out)
{
    __shared__ float lds_h[2][2][2][64];   // [parity][pair][half][lane]
    __shared__ float lds_z[2][4][64];      // [parity][wave][lane]

    const int tid  = threadIdx.x;
    const int lane = tid & 63;
    const int w    = tid >> 6;          // 0..3
    const int pair = w >> 1;            // h-column half
    const int half = w & 1;             // mm1 K-half
    const int b    = blockIdx.x;
    const int ch   = lane & 31;
    const int col  = 64 * pair + lane;  // this lane's h column (no duplication)

    // ---- W1 rows [48*half, 48*half+48) for this column, in registers ----
    float w1c[48];
#pragma unroll
    for (int i = 0; i < 48; ++i) w1c[i] = W1[(48 * half + i) * 128 + col];
    // ---- W2 rows [32w, 32w+32): w2c[j] = W2[32w+j][lane] ----
    float w2c[32];
#pragma unroll
    for (int j = 0; j < 32; ++j) w2c[j] = W2[(32 * w + j) * 64 + lane];
    float b1c = b1[col];
    float b2m = b2[lane];

    // pin against loop-remat (r7 failure mode; belt+suspenders with waves_per_eu)
#pragma unroll
    for (int i = 0; i < 48; ++i) asm volatile("" : "+v"(w1c[i]));
#pragma unroll
    for (int j = 0; j < 32; ++j) asm volatile("" : "+v"(w2c[j]));
    asm volatile("" : "+v"(b1c));
    asm volatile("" : "+v"(b2m));

    const float* a_ptr = cA + (size_t)b * SEGS * CIN;
    const float* bp    = cB + (size_t)b * SEGS * CIN;
    const float* cp    = cC + (size_t)b * SEGS * CIN;
    const float* dp    = cD + (size_t)b * SEGS * CIN;

    // ---- z0 = X(0) @ W_init + b_init  (identical in all waves) ----
    float z = b_init[lane];
    {
        float a0 = a_ptr[ch];
#pragma unroll
        for (int i = 0; i < 32; ++i)
            z = fmaf(rl(a0, i), W_init[i * 64 + lane], z);
    }

    const int fi = final_index[b];

    // current-segment coeffs: only half==1 waves evaluate the spline
    float acur = 0.f, bcur = 0.f, ccur = 0.f, dcur = 0.f;
    if (half) { acur = a_ptr[ch]; bcur = bp[ch]; ccur = cp[ch]; dcur = dp[ch]; }
    float k1 = 0.f, k2 = 0.f, k3 = 0.f, k4 = 0.f;

#define MM_STAGE(YS, XC, PAR, KOUT) do {                                     \
    float hp = 0.f, hq = 0.f;                                                \
    if (half == 0) {                                                         \
        _Pragma("unroll")                                                    \
        for (int i = 0; i < 48; i += 2) {                                    \
            float u0 = rl((YS), i), u1 = rl((YS), i + 1);                    \
            hp = fmaf(u0, w1c[i], hp);                                       \
            hq = fmaf(u1, w1c[i + 1], hq);                                   \
        }                                                                    \
    } else {                                                                 \
        _Pragma("unroll")                                                    \
        for (int i = 0; i < 16; i += 2) {                                    \
            float u0 = rl((YS), 48 + i), u1 = rl((YS), 49 + i);              \
            hp = fmaf(u0, w1c[i], hp);                                       \
            hq = fmaf(u1, w1c[i + 1], hq);                                   \
        }                                                                    \
        _Pragma("unroll")                                                    \
        for (int i = 0; i < 32; i += 2) {                                    \
            float u0 = rl((XC), i), u1 = rl((XC), i + 1);                    \
            hp = fmaf(u0, w1c[16 + i], hp);                                  \
            hq = fmaf(u1, w1c[17 + i], hq);                                  \
        }                                                                    \
    }                                                                        \
    lds_h[PAR][pair][half][lane] = hp + hq;                                  \
    __syncthreads();                                                         \
    float h = tanhf_fast(hp + hq + lds_h[PAR][pair][half ^ 1][lane] + b1c);  \
    float zp = 0.f, zq = 0.f;                                                \
    _Pragma("unroll")                                                        \
    for (int j = 0; j < 32; j += 2) {                                        \
        zp = fmaf(rl(h, 32 * half + j),     w2c[j],     zp);                 \
        zq = fmaf(rl(h, 32 * half + j + 1), w2c[j + 1], zq);                 \
    }                                                                        \
    lds_z[PAR][w][lane] = zp + zq;                                           \
    __syncthreads();                                                         \
    float zs = lds_z[PAR][0][lane] + lds_z[PAR][1][lane]                     \
             + lds_z[PAR][2][lane] + lds_z[PAR][3][lane] + b2m;              \
    KOUT = tanhf_fast(zs);                                                   \
} while (0)

    for (int t = 0; t < fi; ++t) {
        // spline points (half==1 waves only; others keep zeros, never read)
        float x0 = 0.f, x13 = 0.f, x23 = 0.f, xb = 0.f;
        float anx = 0.f, bnx = 0.f, cnx = 0.f, dnx = 0.f;
        if (half) {
            x0  = acur;
            float i13 = fmaf(dcur, 1.0f / 9.0f, 0.5f * ccur);
            x13 = fmaf(fmaf(i13, 1.0f / 3.0f, bcur), 1.0f / 3.0f, acur);
            float i23 = fmaf(dcur, 2.0f / 9.0f, 0.5f * ccur);
            x23 = fmaf(fmaf(i23, 2.0f / 3.0f, bcur), 2.0f / 3.0f, acur);
            float xbl = acur + (bcur + (0.5f * ccur + dcur * (1.0f / 3.0f)));
            // prefetch next segment (first use: stage 3 / next iter top)
            const int tn  = (t + 1 < SEGS) ? (t + 1) : (SEGS - 1);
            const int off = tn * CIN + ch;
            anx = a_ptr[off]; bnx = bp[off]; cnx = cp[off]; dnx = dp[off];
            xb  = (t < SEGS - 1) ? anx : xbl;
        }

        MM_STAGE(z, x0, 0, k1);
        float ys1 = fmaf(k1, 1.0f / 3.0f, z);
        MM_STAGE(ys1, x13, 1, k2);
        float ys2 = z + (k2 - k1 * (1.0f / 3.0f));
        MM_STAGE(ys2, x23, 0, k3);
        float ys3 = z + (k1 - k2 + k3);
        MM_STAGE(ys3, xb, 1, k4);

        z += (k1 + 3.0f * (k2 + k3) + k4) * 0.125f;
        if (half) { acur = anx; bcur = bnx; ccur = cnx; dcur = dnx; }
    }

    // ---- out[b] = z_fi @ W_out + b_out ----
    if (w == 0 && lane < 10) {
        float acc = b_out[lane];
#pragma unroll
        for (int m = 0; m < 64; ++m)
            acc = fmaf(rl(z, m), W_out[m * 10 + lane], acc);
        out[b * 10 + lane] = acc;
    }
}

extern "C" void kernel_launch(void* const* d_in, const int* in_sizes, int n_in,
                              void* d_out, int out_size, void* d_ws, size_t ws_size,
                              hipStream_t stream) {
    const float* cA     = (const float*)d_in[1];
    const float* cBc    = (const float*)d_in[2];
    const float* cCc    = (const float*)d_in[3];
    const float* cDc    = (const float*)d_in[4];
    const int*   fidx   = (const int*)d_in[5];
    const float* W_init = (const float*)d_in[6];
    const float* b_init = (const float*)d_in[7];
    const float* W1     = (const float*)d_in[8];
    const float* b1     = (const float*)d_in[9];
    const float* W2     = (const float*)d_in[10];
    const float* b2     = (const float*)d_in[11];
    const float* W_out  = (const float*)d_in[12];
    const float* b_out  = (const float*)d_in[13];

    node_kernel<<<dim3(NSEQ), dim3(256), 0, stream>>>(
        cA, cBc, cCc, cDc, fidx, W_init, b_init, W1, b1, W2, b2, W_out, b_out,
        (float*)d_out);
}

// Round 10
// 1454.134 us; speedup vs baseline: 1.4725x; 1.4725x over previous
//
#include <hip/hip_runtime.h>
#include <hip/hip_bf16.h>

#define NSEQ 512
#define SEGS 511     // L-1
#define CIN  32

__device__ __forceinline__ float rl(float v, int lane) {
    return __int_as_float(__builtin_amdgcn_readlane(__float_as_int(v), lane));
}

__device__ __forceinline__ float tanhf_fast(float x) {
    // tanh(x) = sign(x) * (1 - e) / (1 + e),  e = exp(-2|x|)  — no overflow path
    float ax = fabsf(x);
    float e = __expf(-2.0f * ax);
#if __has_builtin(__builtin_amdgcn_rcpf)
    float r = (1.0f - e) * __builtin_amdgcn_rcpf(1.0f + e);
#else
    float r = (1.0f - e) / (1.0f + e);
#endif
    return copysignf(r, x);
}

// LDS-visibility-only barrier: does NOT drain vmcnt, so global prefetch
// loads stay in flight across it (__syncthreads would emit
// s_waitcnt vmcnt(0) lgkmcnt(0) and kill the prefetch cover every stage).
__device__ __forceinline__ void barrier_lds() {
    asm volatile("s_waitcnt lgkmcnt(0)\n\ts_barrier" ::: "memory");
}

// Block = ONE sequence x 2 waves (128 thr), grid = 512. r8 structure
// (weights register-resident via amdgpu_waves_per_eu(1,1) + opaque pins;
// mm1 column-split, mm2 K-split with one 512B LDS exchange per stage).
//
// r10 changes vs r8 (path cuts only, identical arithmetic):
//  1. in-loop barriers keep vmcnt in flight (barrier_lds) -> the per-step
//     coeff prefetch finally covers its latency (use at stage 3).
//  2. spline-point + prefetch block moved into stage 0's write->barrier
//     shadow (off the step-top critical path).
// Occupancy deliberately 1 wave/SIMD: r8 (1/SIMD) beat both r9 (2/SIMD,
// issue>50% so co-wave stretches the straggler) and r5/r6 (LDS streaming).
__attribute__((amdgpu_waves_per_eu(1, 1)))
__global__ __launch_bounds__(128) void node_kernel(
    const float* __restrict__ cA, const float* __restrict__ cB,
    const float* __restrict__ cC, const float* __restrict__ cD,
    const int*   __restrict__ final_index,
    const float* __restrict__ W_init, const float* __restrict__ b_init,
    const float* __restrict__ W1, const float* __restrict__ b1,
    const float* __restrict__ W2, const float* __restrict__ b2,
    const float* __restrict__ W_out, const float* __restrict__ b_out,
    float* __restrict__ out)
{
    __shared__ float zz[2][2][64];         // [parity][wave][lane] mm2 partials

    const int tid  = threadIdx.x;
    const int lane = tid & 63;
    const int w    = tid >> 6;          // 0..1
    const int b    = blockIdx.x;
    const int ch   = lane & 31;
    const int col  = 64 * w + lane;     // this lane's h column (all distinct)

    // ---- W1 column in registers: w1c[i] = W1[i][col] (coalesced 256B/wave) ----
    float w1c[96];
#pragma unroll
    for (int i = 0; i < 96; ++i) w1c[i] = W1[i * 128 + col];
    // ---- W2 slice: w2c[j] = W2[64w+j][lane] ----
    float w2c[64];
#pragma unroll
    for (int j = 0; j < 64; ++j) w2c[j] = W2[(64 * w + j) * 64 + lane];
    float b1c = b1[col];
    float b2m = b2[lane];

    // pin: results opaque -> cannot be rematerialized from memory in the loop
#pragma unroll
    for (int i = 0; i < 96; ++i) asm volatile("" : "+v"(w1c[i]));
#pragma unroll
    for (int j = 0; j < 64; ++j) asm volatile("" : "+v"(w2c[j]));
    asm volatile("" : "+v"(b1c));
    asm volatile("" : "+v"(b2m));

    const float* a_ptr = cA + (size_t)b * SEGS * CIN;
    const float* bp    = cB + (size_t)b * SEGS * CIN;
    const float* cp    = cC + (size_t)b * SEGS * CIN;
    const float* dp    = cD + (size_t)b * SEGS * CIN;

    // ---- z0 = X(0) @ W_init + b_init  (replicated identically in both waves) ----
    float z = b_init[lane];
    {
        float a0 = a_ptr[ch];
#pragma unroll
        for (int i = 0; i < 32; ++i)
            z = fmaf(rl(a0, i), W_init[i * 64 + lane], z);
    }

    const int fi = final_index[b];      // ONE seq per block: tight loop bound

    // current-segment coeffs (lanes 0..31 meaningful; per-wave copy)
    float acur = a_ptr[ch], bcur = bp[ch], ccur = cp[ch], dcur = dp[ch];
    float k1 = 0.f, k2 = 0.f, k3 = 0.f, k4 = 0.f;

    __syncthreads();

// MID runs between the ds_write and the barrier: hidden behind the other
// wave's arrival + LDS latency instead of sitting on the critical path.
#define MM_STAGE(YS, XC, PAR, KOUT, MID) do {                                \
    float h0 = 0.f, h1 = 0.f;                                                \
    _Pragma("unroll")                                                        \
    for (int i = 0; i < 64; i += 2) {                                        \
        float u0 = rl((YS), i), u1 = rl((YS), i + 1);                        \
        h0 = fmaf(u0, w1c[i], h0);                                           \
        h1 = fmaf(u1, w1c[i + 1], h1);                                       \
    }                                                                        \
    _Pragma("unroll")                                                        \
    for (int i = 0; i < 32; i += 2) {                                        \
        float u0 = rl((XC), i), u1 = rl((XC), i + 1);                        \
        h0 = fmaf(u0, w1c[64 + i], h0);                                      \
        h1 = fmaf(u1, w1c[64 + i + 1], h1);                                  \
    }                                                                        \
    float h = tanhf_fast(h0 + h1 + b1c);  /* this lane's col = 64w+lane */   \
    float zp = 0.f, zq = 0.f;                                                \
    _Pragma("unroll")                                                        \
    for (int j = 0; j < 64; j += 2) {                                        \
        zp = fmaf(rl(h, j),     w2c[j],     zp);                             \
        zq = fmaf(rl(h, j + 1), w2c[j + 1], zq);                             \
    }                                                                        \
    zz[PAR][w][lane] = zp + zq;                                              \
    MID;                                                                     \
    barrier_lds();                                                           \
    float zo = zz[PAR][w ^ 1][lane];                                         \
    KOUT = tanhf_fast(zp + zq + zo + b2m);                                   \
} while (0)

    for (int t = 0; t < fi; ++t) {
        float x13, x23, xbl;
        float anx, bnx, cnx, dnx;

        // stage 0 (x0 = acur, already in registers); spline points + next-seg
        // prefetch issue in the write->barrier shadow. xb's anx use is 3
        // stages away (~4800 cyc of cover, no barrier drains vmcnt anymore).
        MM_STAGE(z, acur, 0, k1, {
            float i13 = fmaf(dcur, 1.0f / 9.0f, 0.5f * ccur);
            x13 = fmaf(fmaf(i13, 1.0f / 3.0f, bcur), 1.0f / 3.0f, acur);
            float i23 = fmaf(dcur, 2.0f / 9.0f, 0.5f * ccur);
            x23 = fmaf(fmaf(i23, 2.0f / 3.0f, bcur), 2.0f / 3.0f, acur);
            xbl = acur + (bcur + (0.5f * ccur + dcur * (1.0f / 3.0f)));
            const int tn  = (t + 1 < SEGS) ? (t + 1) : (SEGS - 1);
            const int off = tn * CIN + ch;
            anx = a_ptr[off]; bnx = bp[off]; cnx = cp[off]; dnx = dp[off];
        });
        float ys1 = fmaf(k1, 1.0f / 3.0f, z);
        MM_STAGE(ys1, x13, 1, k2, {});
        float ys2 = z + (k2 - k1 * (1.0f / 3.0f));
        MM_STAGE(ys2, x23, 0, k3, {});
        float xb  = (t < SEGS - 1) ? anx : xbl;   // vmcnt wait lands here
        float ys3 = z + (k1 - k2 + k3);
        MM_STAGE(ys3, xb, 1, k4, {});

        z += (k1 + 3.0f * (k2 + k3) + k4) * 0.125f;
        acur = anx; bcur = bnx; ccur = cnx; dcur = dnx;
    }

    // ---- out[b] = z_fi @ W_out + b_out ----
    if (w == 0 && lane < 10) {
        float acc = b_out[lane];
#pragma unroll
        for (int m = 0; m < 64; ++m)
            acc = fmaf(rl(z, m), W_out[m * 10 + lane], acc);
        out[b * 10 + lane] = acc;
    }
}

extern "C" void kernel_launch(void* const* d_in, const int* in_sizes, int n_in,
                              void* d_out, int out_size, void* d_ws, size_t ws_size,
                              hipStream_t stream) {
    const float* cA     = (const float*)d_in[1];
    const float* cBc    = (const float*)d_in[2];
    const float* cCc    = (const float*)d_in[3];
    const float* cDc    = (const float*)d_in[4];
    const int*   fidx   = (const int*)d_in[5];
    const float* W_init = (const float*)d_in[6];
    const float* b_init = (const float*)d_in[7];
    const float* W1     = (const float*)d_in[8];
    const float* b1     = (const float*)d_in[9];
    const float* W2     = (const float*)d_in[10];
    const float* b2     = (const float*)d_in[11];
    const float* W_out  = (const float*)d_in[12];
    const float* b_out  = (const float*)d_in[13];

    node_kernel<<<dim3(NSEQ), dim3(128), 0, stream>>>(
        cA, cBc, cCc, cDc, fidx, W_init, b_init, W1, b1, W2, b2, W_out, b_out,
        (float*)d_out);
}